// Round 8
// baseline (154.367 us; speedup 1.0000x reference)
//
#include <hip/hip_runtime.h>

#define BB 8
#define CC 256
#define HH 64
#define WW 64
#define RED 64
#define HW 4096   // HH*WW
#define XS 68     // LDS row stride for channel-chunk tile
#define LS 68     // LDS row stride for image planes in invol_dw

// ---- tiny transpose: w_red [64,256] (o-major) -> wt [256,64] (c-major) ----
// Restores the contiguous-in-o layout so dw_kern's inner loop is ONE
// s_load_dwordx8 per c instead of 8 strided s_load_dword (R6 regression).
__global__ __launch_bounds__(256) void transpose_wred(const float* __restrict__ w_red,
                                                      float* __restrict__ wt) {
    int idx = blockIdx.x * 256 + threadIdx.x;   // 64 blocks * 256 = 16384
    int o = idx >> 8, c = idx & 255;
    wt[c * RED + o] = w_red[idx];
}

// ---- fused dwconv1 + involution-kernel-generation, software-pipelined ----
// One block per (row h, batch b): 512 threads. Double-buffered LDS: phase A of
// chunk k+1 overlaps phase B of chunk k. Weights via scalar path, contiguous
// 8-float rows (s_load_dwordx8). h XCD-swizzled for halo L2 reuse.
__global__ __launch_bounds__(512) void dw_kern(const float* __restrict__ x,
                                               const float* __restrict__ w_in,
                                               const float* __restrict__ b_in,
                                               const float* __restrict__ wt,      // [256][64]
                                               const float* __restrict__ b_red,
                                               const float* __restrict__ w_span,  // [9][64]
                                               const float* __restrict__ b_span,
                                               float* __restrict__ x1,
                                               float* __restrict__ kern) {
    __shared__ float xs[2][64 * XS];             // 2 x 17.4 KiB
    __shared__ float part[8 * 9 * 64];           // 18 KiB
    const int t  = threadIdx.x;
    const int bx = blockIdx.x;
    const int h  = ((bx & 7) << 3) | (bx >> 3);  // XCD band swizzle (perf only)
    const int b  = blockIdx.y;
    const int px = t & 63;
    const int og = t >> 6;
    const int o0 = __builtin_amdgcn_readfirstlane(og << 3);  // -> SGPR
    const int q  = t & 15;
    const int w0 = q << 2;
    const int cr = t >> 4;                       // 0..31

    float acc[8];
    #pragma unroll
    for (int i = 0; i < 8; i++) acc[i] = 0.f;

    // phase A for one 64-channel chunk -> LDS buf + global x1
    auto phaseA = [&](int c0, int buf) {
        #pragma unroll
        for (int s = 0; s < 2; s++) {
            const int cl = s * 32 + cr;          // 0..63 within chunk
            const int cc = c0 + cl;
            const float* xp = x + ((size_t)(b * CC + cc)) * HW;
            const float* wp = w_in + cc * 9;
            const float bb = b_in[cc];
            float4 a4 = make_float4(bb, bb, bb, bb);
            #pragma unroll
            for (int ky = 0; ky < 3; ky++) {
                int hh = h + ky - 1;
                if (hh < 0 || hh >= HH) continue;   // block-uniform
                const float* row = xp + hh * WW + w0;
                float4 v = *(const float4*)row;
                float lf = (w0 > 0)      ? row[-1] : 0.f;
                float rt = (w0 + 4 < WW) ? row[4]  : 0.f;
                float k0 = wp[ky * 3 + 0], k1 = wp[ky * 3 + 1], k2 = wp[ky * 3 + 2];
                a4.x = fmaf(k0, lf,  a4.x); a4.y = fmaf(k0, v.x, a4.y);
                a4.z = fmaf(k0, v.y, a4.z); a4.w = fmaf(k0, v.z, a4.w);
                a4.x = fmaf(k1, v.x, a4.x); a4.y = fmaf(k1, v.y, a4.y);
                a4.z = fmaf(k1, v.z, a4.z); a4.w = fmaf(k1, v.w, a4.w);
                a4.x = fmaf(k2, v.y, a4.x); a4.y = fmaf(k2, v.z, a4.y);
                a4.z = fmaf(k2, v.w, a4.z); a4.w = fmaf(k2, rt,  a4.w);
            }
            *(float4*)&xs[buf][cl * XS + w0] = a4;
            *(float4*)(x1 + ((size_t)(b * CC + cc)) * HW + h * WW + w0) = a4;
        }
    };

    phaseA(0, 0);
    __syncthreads();
    for (int k = 0; k < 4; k++) {
        if (k < 3) phaseA((k + 1) << 6, (k + 1) & 1);   // prefetch next chunk
        // phase B: reduce-GEMM from current buffer; weights contiguous in o
        // -> s_load_dwordx8, no per-o strided scalar loads (this was the R6 bug)
        const float* wrow = wt + (k << 6) * RED + o0;   // SGPR-uniform base
        const float* xb = &xs[k & 1][0];
        #pragma unroll 8
        for (int c = 0; c < 64; c++) {
            float xv = xb[c * XS + px];          // stride-1 across lanes: conflict-free
            #pragma unroll
            for (int i = 0; i < 8; i++)
                acc[i] = fmaf(wrow[c * RED + i], xv, acc[i]);
        }
        __syncthreads();
    }

    // epilogue: relu + span contraction + cross-o-group reduction
    float kk[9];
    #pragma unroll
    for (int j = 0; j < 9; j++) kk[j] = 0.f;
    #pragma unroll
    for (int i = 0; i < 8; i++) {
        float r = fmaxf(acc[i] + b_red[o0 + i], 0.f);
        #pragma unroll
        for (int j = 0; j < 9; j++) kk[j] = fmaf(w_span[j * RED + o0 + i], r, kk[j]);
    }
    #pragma unroll
    for (int j = 0; j < 9; j++) part[(og * 9 + j) * 64 + px] = kk[j];
    __syncthreads();
    if (og == 0) {
        float* kp = kern + (size_t)b * 9 * HW + h * WW + px;
        #pragma unroll
        for (int j = 0; j < 9; j++) {
            float s = b_span[j];
            #pragma unroll
            for (int g = 0; g < 8; g++) s += part[(g * 9 + j) * 64 + px];
            kp[j * HW] = s;
        }
    }
}

// ---- fused involution-apply + dwconv3x3 (out) ----
// One block per (c,b) plane: 256 threads x 16 px. x1 staged in LDS, involution
// result kept in LDS, dwconv2 consumes it. Saves the 67 MB y round-trip.
__global__ __launch_bounds__(256) void invol_dw(const float* __restrict__ x1,
                                                const float* __restrict__ kern,
                                                const float* __restrict__ w_out,
                                                const float* __restrict__ b_out,
                                                float* __restrict__ out) {
    __shared__ float xs[HH * LS];                // 17.4 KiB
    __shared__ float ys[HH * LS];                // 17.4 KiB
    const int t  = threadIdx.x;
    const int q  = t & 15;
    const int w0 = q << 2;
    const int r  = t >> 4;                       // 0..15
    const int c = blockIdx.x, b = blockIdx.y;
    const float* xp = x1 + ((size_t)(b * CC + c)) * HW;

    #pragma unroll
    for (int i = 0; i < 4; i++) {
        int h = r + (i << 4);
        *(float4*)&xs[h * LS + w0] = *(const float4*)(xp + h * WW + w0);
    }
    __syncthreads();

    const float* kp = kern + (size_t)b * 9 * HW;
    #pragma unroll
    for (int i = 0; i < 4; i++) {
        int h  = r + (i << 4);
        int hw = h * WW + w0;
        float4 acc = make_float4(0.f, 0.f, 0.f, 0.f);
        #pragma unroll
        for (int ky = 0; ky < 3; ky++) {
            int hh = h + ky - 1;
            if (hh < 0 || hh >= HH) continue;
            const float* row = &xs[hh * LS + w0];
            float4 v = *(const float4*)row;
            float lf = (w0 > 0)      ? row[-1] : 0.f;
            float rt = (w0 + 4 < WW) ? row[4]  : 0.f;
            float4 k0 = *(const float4*)(kp + (ky * 3 + 0) * HW + hw);
            float4 k1 = *(const float4*)(kp + (ky * 3 + 1) * HW + hw);
            float4 k2 = *(const float4*)(kp + (ky * 3 + 2) * HW + hw);
            acc.x = fmaf(k0.x, lf,  acc.x); acc.y = fmaf(k0.y, v.x, acc.y);
            acc.z = fmaf(k0.z, v.y, acc.z); acc.w = fmaf(k0.w, v.z, acc.w);
            acc.x = fmaf(k1.x, v.x, acc.x); acc.y = fmaf(k1.y, v.y, acc.y);
            acc.z = fmaf(k1.z, v.z, acc.z); acc.w = fmaf(k1.w, v.w, acc.w);
            acc.x = fmaf(k2.x, v.y, acc.x); acc.y = fmaf(k2.y, v.z, acc.y);
            acc.z = fmaf(k2.z, v.w, acc.z); acc.w = fmaf(k2.w, rt,  acc.w);
        }
        *(float4*)&ys[h * LS + w0] = acc;
    }
    __syncthreads();

    const float* wp = w_out + c * 9;             // block-uniform -> s_load
    const float bb = b_out[c];
    float* op = out + ((size_t)(b * CC + c)) * HW;
    #pragma unroll
    for (int i = 0; i < 4; i++) {
        int h = r + (i << 4);
        float4 acc = make_float4(bb, bb, bb, bb);
        #pragma unroll
        for (int ky = 0; ky < 3; ky++) {
            int hh = h + ky - 1;
            if (hh < 0 || hh >= HH) continue;
            const float* row = &ys[hh * LS + w0];
            float4 v = *(const float4*)row;
            float lf = (w0 > 0)      ? row[-1] : 0.f;
            float rt = (w0 + 4 < WW) ? row[4]  : 0.f;
            float k0 = wp[ky * 3 + 0], k1 = wp[ky * 3 + 1], k2 = wp[ky * 3 + 2];
            acc.x = fmaf(k0, lf,  acc.x); acc.y = fmaf(k0, v.x, acc.y);
            acc.z = fmaf(k0, v.y, acc.z); acc.w = fmaf(k0, v.z, acc.w);
            acc.x = fmaf(k1, v.x, acc.x); acc.y = fmaf(k1, v.y, acc.y);
            acc.z = fmaf(k1, v.z, acc.z); acc.w = fmaf(k1, v.w, acc.w);
            acc.x = fmaf(k2, v.y, acc.x); acc.y = fmaf(k2, v.z, acc.y);
            acc.z = fmaf(k2, v.w, acc.z); acc.w = fmaf(k2, rt,  acc.w);
        }
        *(float4*)(op + h * WW + w0) = acc;
    }
}

extern "C" void kernel_launch(void* const* d_in, const int* in_sizes, int n_in,
                              void* d_out, int out_size, void* d_ws, size_t ws_size,
                              hipStream_t stream) {
    const float* x      = (const float*)d_in[0];
    const float* w_in   = (const float*)d_in[1];
    const float* b_in   = (const float*)d_in[2];
    const float* w_red  = (const float*)d_in[3];
    const float* b_red  = (const float*)d_in[4];
    const float* w_span = (const float*)d_in[5];
    const float* b_span = (const float*)d_in[6];
    const float* w_out  = (const float*)d_in[7];
    const float* b_out  = (const float*)d_in[8];
    float* out = (float*)d_out;

    float* ws   = (float*)d_ws;
    float* x1   = ws;                                  // 8*256*4096 f
    float* kern = x1 + (size_t)BB * CC * HW;           // 8*9*4096 f
    float* wt   = kern + (size_t)BB * 9 * HW;          // 16,384 f

    transpose_wred<<<64, 256, 0, stream>>>(w_red, wt);
    dw_kern<<<dim3(HH, BB), 512, 0, stream>>>(x, w_in, b_in, wt, b_red,
                                              w_span, b_span, x1, kern);
    invol_dw<<<dim3(CC, BB), 256, 0, stream>>>(x1, kern, w_out, b_out, out);
}